// Round 1
// baseline (530.542 us; speedup 1.0000x reference)
//
#include <hip/hip_runtime.h>
#include <math.h>

#define HID 256
#define SEQ 512

// ---------------------------------------------------------------------------
// Phase 1: inp[t][i] = b[i] + sum_j emb[idx[t]][j] * W[i][HID + j]
// One block per timestep t (512 blocks), 256 threads (one per output i).
// emb row staged in LDS; each per-iter LDS read is same-address broadcast.
// ---------------------------------------------------------------------------
__global__ __launch_bounds__(256) void qrnn_phase1(
    const int* __restrict__ idx, const float* __restrict__ emb,
    const float* __restrict__ W, const float* __restrict__ b,
    float* __restrict__ inp)
{
    const int t = blockIdx.x;
    const int i = threadIdx.x;
    __shared__ float xs[HID];
    const size_t row = (size_t)idx[t];
    xs[i] = emb[row * HID + i];
    __syncthreads();

    const float* wr = W + (size_t)i * (2 * HID) + HID;  // Wx row i
    float acc = b[i];
#pragma unroll
    for (int k = 0; k < HID / 4; ++k) {
        const float4 w4 = *reinterpret_cast<const float4*>(wr + k * 4);
        const float4 x4 = *reinterpret_cast<const float4*>(&xs[k * 4]);
        acc = fmaf(w4.x, x4.x, acc);
        acc = fmaf(w4.y, x4.y, acc);
        acc = fmaf(w4.z, x4.z, acc);
        acc = fmaf(w4.w, x4.w, acc);
    }
    inp[t * HID + i] = acc;
}

// DPP add: v + v_from_partner_lane. ctrl: 0xB1 = quad_perm(1,0,3,2) = xor1,
// 0x4E = quad_perm(2,3,0,1) = xor2, 0x141 = row_half_mirror = xor7 within
// each aligned 8-lane group. All VALU-pipe (no LDS traffic).
template <int CTRL>
__device__ __forceinline__ float dpp_add(float v)
{
    int x = __builtin_amdgcn_update_dpp(0, __float_as_int(v), CTRL, 0xF, 0xF, true);
    return v + __int_as_float(x);
}

// ---------------------------------------------------------------------------
// Phase 2: sequential scan, single block of 256 threads (4 waves).
// Thread layout: g = tid>>3 (32 groups of 8 lanes), r = tid&7.
// Group g owns outputs i in [8g, 8g+8); lane r owns j in [32r, 32r+32).
// Wh tile (8 rows x 32 cols = 256 VGPRs) held in registers for all 512 steps.
// h double-buffered in LDS with XOR swizzle: word(j) = j ^ (((j>>5)&7)<<2)
// so the 8 distinct float4 addresses per wave-read hit 8 distinct bank groups
// (unswizzled, all r*32 offsets alias to bank 0 -> 8-way conflict).
// ---------------------------------------------------------------------------
__global__ __launch_bounds__(256) void qrnn_phase2(
    const float* __restrict__ W, const float* __restrict__ inp,
    float* __restrict__ out)
{
    const int tid = threadIdx.x;
    const int r = tid & 7;
    const int g = tid >> 3;

    __shared__ float hbuf[2][HID];

    // h0 = 0 (swizzle irrelevant for zeros, but buffer 0 fully written)
    hbuf[0][tid] = 0.0f;

    // Load Wh tile into registers: wv[m][k] = W[8g+m][32r + 4k .. +3]
    float4 wv[8][8];
#pragma unroll
    for (int m = 0; m < 8; ++m) {
        const float* wrow = W + (size_t)(g * 8 + m) * (2 * HID) + r * 32;
#pragma unroll
        for (int k = 0; k < 8; ++k)
            wv[m][k] = *reinterpret_cast<const float4*>(wrow + k * 4);
    }

    float ip = inp[tid];  // inp[0][tid]
    __syncthreads();

    int cur = 0;
    float h = 0.0f;
#pragma unroll 1
    for (int t = 0; t < SEQ; ++t) {
        // Read this lane's 32 h values (8 swizzled float4 reads, conflict-free)
        const float* hb = &hbuf[cur][0];
        float4 h4[8];
#pragma unroll
        for (int k = 0; k < 8; ++k)
            h4[k] = *reinterpret_cast<const float4*>(hb + r * 32 + (((k ^ r) & 7) << 2));

        // Prefetch next step's inp while FMAs run
        float ip_next = (t + 1 < SEQ) ? inp[(t + 1) * HID + tid] : 0.0f;

        // 8 partial dots (32 terms each) -> 256 FMAs, 8 independent chains
        float acc[8];
#pragma unroll
        for (int m = 0; m < 8; ++m) {
            float a = 0.0f;
#pragma unroll
            for (int k = 0; k < 8; ++k) {
                a = fmaf(wv[m][k].x, h4[k].x, a);
                a = fmaf(wv[m][k].y, h4[k].y, a);
                a = fmaf(wv[m][k].z, h4[k].z, a);
                a = fmaf(wv[m][k].w, h4[k].w, a);
            }
            acc[m] = a;
        }

        // Butterfly reduce across the 8-lane group (DPP, VALU pipe)
#pragma unroll
        for (int m = 0; m < 8; ++m) {
            acc[m] = dpp_add<0xB1>(acc[m]);   // xor 1
            acc[m] = dpp_add<0x4E>(acc[m]);   // xor 2
            acc[m] = dpp_add<0x141>(acc[m]);  // xor 7
        }

        // Lane r picks output m = r (static 3-level mux, no scratch)
        float s0 = (r & 1) ? acc[1] : acc[0];
        float s1 = (r & 1) ? acc[3] : acc[2];
        float s2 = (r & 1) ? acc[5] : acc[4];
        float s3 = (r & 1) ? acc[7] : acc[6];
        float u0 = (r & 2) ? s1 : s0;
        float u1 = (r & 2) ? s3 : s2;
        float d  = (r & 4) ? u1 : u0;

        d += ip;
        // tanh(d) = 1 - 2/(exp(2d)+1)
        float e = __expf(2.0f * d);
        h = 1.0f - 2.0f / (e + 1.0f);

        // Write h_new[tid] to the other buffer (swizzled word)
        hbuf[cur ^ 1][tid ^ (((tid >> 5) & 7) << 2)] = h;

        ip = ip_next;
        cur ^= 1;
        __syncthreads();
    }

    out[tid] = h;  // thread tid computed h_final[tid] in the last step
}

extern "C" void kernel_launch(void* const* d_in, const int* in_sizes, int n_in,
                              void* d_out, int out_size, void* d_ws, size_t ws_size,
                              hipStream_t stream)
{
    const int*   idx = (const int*)d_in[0];
    const float* emb = (const float*)d_in[1];
    const float* W   = (const float*)d_in[2];
    const float* b   = (const float*)d_in[3];
    float* out = (float*)d_out;
    float* inp = (float*)d_ws;  // SEQ*HID*4 = 512 KB scratch

    qrnn_phase1<<<SEQ, HID, 0, stream>>>(idx, emb, W, b, inp);
    qrnn_phase2<<<1, HID, 0, stream>>>(W, inp, out);
}

// Round 2
// 331.495 us; speedup vs baseline: 1.6005x; 1.6005x over previous
//
#include <hip/hip_runtime.h>
#include <math.h>

#define HID 256
#define SEQ 512

// ---------------------------------------------------------------------------
// Phase 1: inp[t][i] = b[i] + sum_j emb[idx[t]][j] * W[i][HID + j]
// One block per timestep t (512 blocks), 256 threads (one per output i).
// ---------------------------------------------------------------------------
__global__ __launch_bounds__(256) void qrnn_phase1(
    const int* __restrict__ idx, const float* __restrict__ emb,
    const float* __restrict__ W, const float* __restrict__ b,
    float* __restrict__ inp)
{
    const int t = blockIdx.x;
    const int i = threadIdx.x;
    __shared__ float xs[HID];
    const size_t row = (size_t)idx[t];
    xs[i] = emb[row * HID + i];
    __syncthreads();

    const float* wr = W + (size_t)i * (2 * HID) + HID;  // Wx row i
    float acc = b[i];
#pragma unroll
    for (int k = 0; k < HID / 4; ++k) {
        const float4 w4 = *reinterpret_cast<const float4*>(wr + k * 4);
        const float4 x4 = *reinterpret_cast<const float4*>(&xs[k * 4]);
        acc = fmaf(w4.x, x4.x, acc);
        acc = fmaf(w4.y, x4.y, acc);
        acc = fmaf(w4.z, x4.z, acc);
        acc = fmaf(w4.w, x4.w, acc);
    }
    inp[t * HID + i] = acc;
}

// DPP add across lanes: 0xB1 = xor1, 0x4E = xor2, 0x141 = row_half_mirror
// (= xor7 within each aligned 8-lane group). VALU pipe, no LDS traffic.
template <int CTRL>
__device__ __forceinline__ float dpp_add(float v)
{
    int x = __builtin_amdgcn_update_dpp(0, __float_as_int(v), CTRL, 0xF, 0xF, true);
    return v + __int_as_float(x);
}

// ---------------------------------------------------------------------------
// Phase 2: sequential scan, single block of 512 threads (8 waves, 2/SIMD).
// Thread layout: g = tid>>3 (64 groups of 8 lanes), r = tid&7.
// Group g owns output rows i in [4g, 4g+4); lane r owns cols j in [32r,32r+32).
// Weight tile per thread: 4 rows x 32 cols = 128 VGPRs -> total ~190 VGPRs,
// fits the 256-VGPR/wave budget needed for 8 waves/CU, so the compiler keeps
// it register-resident (round-1 failure mode: 8x32 tile = 256 VGPRs forced
// rematerialization from L2 every step, ~2000 cy/step of hidden L2 traffic).
// h double-buffered in LDS, XOR-swizzled: word(j) = j ^ (((j>>5)&7)<<2)
// -> both the 8 float4 reads/lane and the h-writes are bank-conflict-free.
// ---------------------------------------------------------------------------
__global__ __launch_bounds__(512, 2) void qrnn_phase2(
    const float* __restrict__ W, const float* __restrict__ inp,
    float* __restrict__ out)
{
    const int tid = threadIdx.x;
    const int r = tid & 7;
    const int g = tid >> 3;     // [0, 64)
    const int m_out = r & 3;    // which of the group's 4 rows this lane picks
    const int i_out = 4 * g + m_out;

    __shared__ float hbuf[2][HID];

    if (tid < HID) hbuf[0][tid] = 0.0f;

    // Weight tile: wv[m][k] = W[(4g+m)][32r + 4k .. +3]  (Wh part, cols<HID)
    float4 wv[4][8];
#pragma unroll
    for (int m = 0; m < 4; ++m) {
        const float* wrow = W + (size_t)(4 * g + m) * (2 * HID) + r * 32;
#pragma unroll
        for (int k = 0; k < 8; ++k)
            wv[m][k] = *reinterpret_cast<const float4*>(wrow + k * 4);
    }

    float ip = inp[i_out];  // inp[0][i_out]
    __syncthreads();

    int cur = 0;
    float h = 0.0f;
#pragma unroll 1
    for (int t = 0; t < SEQ; ++t) {
        // This lane's 32 h values: 8 swizzled float4 reads, conflict-free
        const float* hb = &hbuf[cur][0];
        float4 h4[8];
#pragma unroll
        for (int k = 0; k < 8; ++k)
            h4[k] = *reinterpret_cast<const float4*>(hb + r * 32 + (((k ^ r) & 7) << 2));

        // Prefetch next step's inp while FMAs run (completes under FMA phase;
        // __syncthreads at loop end drains vmcnt anyway)
        float ip_next = (t + 1 < SEQ) ? inp[(t + 1) * HID + i_out] : 0.0f;

        // 4 partial dots (32 terms each) -> 128 FMAs, 4 independent chains
        float acc[4];
#pragma unroll
        for (int m = 0; m < 4; ++m) {
            float a = 0.0f;
#pragma unroll
            for (int k = 0; k < 8; ++k) {
                a = fmaf(wv[m][k].x, h4[k].x, a);
                a = fmaf(wv[m][k].y, h4[k].y, a);
                a = fmaf(wv[m][k].z, h4[k].z, a);
                a = fmaf(wv[m][k].w, h4[k].w, a);
            }
            acc[m] = a;
        }

        // Butterfly reduce across the 8-lane group (DPP, VALU pipe)
#pragma unroll
        for (int m = 0; m < 4; ++m) {
            acc[m] = dpp_add<0xB1>(acc[m]);   // xor 1
            acc[m] = dpp_add<0x4E>(acc[m]);   // xor 2
            acc[m] = dpp_add<0x141>(acc[m]);  // xor 7
        }

        // Lane picks its row (lanes r and r+4 duplicate row r&3)
        float s0 = (r & 1) ? acc[1] : acc[0];
        float s1 = (r & 1) ? acc[3] : acc[2];
        float d  = (r & 2) ? s1 : s0;

        d += ip;
        // tanh(d) = 1 - 2/(exp(2d)+1)
        float e = __expf(2.0f * d);
        h = 1.0f - 2.0f / (e + 1.0f);

        // r<4 lanes write h_new[i_out] to the other buffer (swizzled word);
        // within a wave the 32 written words permute [32w,32w+32) -> all 32
        // banks, conflict-free.
        if (r < 4)
            hbuf[cur ^ 1][i_out ^ (((i_out >> 5) & 7) << 2)] = h;

        ip = ip_next;
        cur ^= 1;
        __syncthreads();
    }

    if (r < 4) out[i_out] = h;
}

extern "C" void kernel_launch(void* const* d_in, const int* in_sizes, int n_in,
                              void* d_out, int out_size, void* d_ws, size_t ws_size,
                              hipStream_t stream)
{
    const int*   idx = (const int*)d_in[0];
    const float* emb = (const float*)d_in[1];
    const float* W   = (const float*)d_in[2];
    const float* b   = (const float*)d_in[3];
    float* out = (float*)d_out;
    float* inp = (float*)d_ws;  // SEQ*HID*4 = 512 KB scratch

    qrnn_phase1<<<SEQ, HID, 0, stream>>>(idx, emb, W, b, inp);
    qrnn_phase2<<<1, 512, 0, stream>>>(W, inp, out);
}

// Round 3
// 281.155 us; speedup vs baseline: 1.8870x; 1.1790x over previous
//
#include <hip/hip_runtime.h>
#include <math.h>

#define HID 256
#define SEQ 512

typedef float v4f __attribute__((ext_vector_type(4)));

// ---------------------------------------------------------------------------
// Phase 1: inp[t][i] = b[i] + sum_j emb[idx[t]][j] * W[i][HID + j]
// One block per timestep t (512 blocks), 256 threads (one per output i).
// ---------------------------------------------------------------------------
__global__ __launch_bounds__(256) void qrnn_phase1(
    const int* __restrict__ idx, const float* __restrict__ emb,
    const float* __restrict__ W, const float* __restrict__ b,
    float* __restrict__ inp)
{
    const int t = blockIdx.x;
    const int i = threadIdx.x;
    __shared__ float xs[HID];
    const size_t row = (size_t)idx[t];
    xs[i] = emb[row * HID + i];
    __syncthreads();

    const float* wr = W + (size_t)i * (2 * HID) + HID;  // Wx row i
    float acc = b[i];
#pragma unroll
    for (int k = 0; k < HID / 4; ++k) {
        const float4 w4 = *reinterpret_cast<const float4*>(wr + k * 4);
        const float4 x4 = *reinterpret_cast<const float4*>(&xs[k * 4]);
        acc = fmaf(w4.x, x4.x, acc);
        acc = fmaf(w4.y, x4.y, acc);
        acc = fmaf(w4.z, x4.z, acc);
        acc = fmaf(w4.w, x4.w, acc);
    }
    inp[t * HID + i] = acc;
}

// DPP add across lanes: 0xB1 = xor1, 0x4E = xor2, 0x141 = row_half_mirror
// (= xor7 within each aligned 8-lane group). VALU pipe, no LDS traffic.
template <int CTRL>
__device__ __forceinline__ float dpp_add(float v)
{
    int x = __builtin_amdgcn_update_dpp(0, __float_as_int(v), CTRL, 0xF, 0xF, true);
    return v + __int_as_float(x);
}

// Pin 8 float4 values into VGPRs: an asm-defined value cannot be
// rematerialized from its originating load, so regalloc must keep it live
// in registers across the scan loop (round-2 failure: compiler reloaded the
// whole weight tile from L2 every step; VGPR_Count=92 proved nothing stayed).
#define PIN8(a) asm volatile("" : "+v"(a[0]), "+v"(a[1]), "+v"(a[2]), \
                                  "+v"(a[3]), "+v"(a[4]), "+v"(a[5]), \
                                  "+v"(a[6]), "+v"(a[7]))

// ---------------------------------------------------------------------------
// Phase 2: sequential scan, single block of 512 threads (8 waves, 2/SIMD).
// Thread layout: g = tid>>3 (64 groups of 8 lanes), r = tid&7.
// Group g owns output rows i in [4g, 4g+4); lane r owns cols j in [32r,32r+32).
// Weight tile per thread: 4 rows x 32 cols = 128 VGPRs, asm-pinned resident.
// h double-buffered in LDS, XOR-swizzled: word(j) = j ^ (((j>>5)&7)<<2)
// -> reads and writes bank-conflict-free. t-loop manually unrolled 2x so all
// LDS addresses are loop-invariant.
// ---------------------------------------------------------------------------
__global__ __launch_bounds__(512, 2) void qrnn_phase2(
    const float* __restrict__ W, const float* __restrict__ inp,
    float* __restrict__ out)
{
    const int tid = threadIdx.x;
    const int r = tid & 7;
    const int g = tid >> 3;     // [0, 64)
    const int m_out = r & 3;    // which of the group's 4 rows this lane picks
    const int i_out = 4 * g + m_out;

    __shared__ float hbuf[2][HID];

    if (tid < HID) hbuf[0][tid] = 0.0f;

    // Weight tile: wv[m][k] = W[(4g+m)][32r + 4k .. +3]  (Wh part, cols<HID)
    v4f wv[4][8];
#pragma unroll
    for (int m = 0; m < 4; ++m) {
        const float* wrow = W + (size_t)(4 * g + m) * (2 * HID) + r * 32;
#pragma unroll
        for (int k = 0; k < 8; ++k)
            wv[m][k] = *reinterpret_cast<const v4f*>(wrow + k * 4);
    }
    PIN8(wv[0]); PIN8(wv[1]); PIN8(wv[2]); PIN8(wv[3]);

    float ip = inp[i_out];  // inp[0][i_out]
    float h = 0.0f;
    __syncthreads();

    auto step = [&](const float* __restrict__ src, float* __restrict__ dst,
                    int tnext) {
        // This lane's 32 h values: 8 swizzled float4 reads, conflict-free,
        // loop-invariant addresses (src is a compile-time buffer).
        v4f h4[8];
#pragma unroll
        for (int k = 0; k < 8; ++k)
            h4[k] = *reinterpret_cast<const v4f*>(src + r * 32 + (((k ^ r) & 7) << 2));

        // Prefetch next step's inp (branchless; last iter harmlessly reads t=0)
        float ip_next = inp[(tnext & (SEQ - 1)) * HID + i_out];

        // 4 partial dots (32 terms each) -> 128 FMAs, 4 independent chains
        float acc[4];
#pragma unroll
        for (int m = 0; m < 4; ++m) {
            float a = 0.0f;
#pragma unroll
            for (int k = 0; k < 8; ++k) {
                a = fmaf(wv[m][k].x, h4[k].x, a);
                a = fmaf(wv[m][k].y, h4[k].y, a);
                a = fmaf(wv[m][k].z, h4[k].z, a);
                a = fmaf(wv[m][k].w, h4[k].w, a);
            }
            acc[m] = a;
        }

        // Butterfly reduce across the 8-lane group (DPP, VALU pipe)
#pragma unroll
        for (int m = 0; m < 4; ++m) {
            acc[m] = dpp_add<0xB1>(acc[m]);   // xor 1
            acc[m] = dpp_add<0x4E>(acc[m]);   // xor 2
            acc[m] = dpp_add<0x141>(acc[m]);  // xor 7
        }

        // Lane picks its row (lanes r and r+4 duplicate row r&3)
        float s0 = (r & 1) ? acc[1] : acc[0];
        float s1 = (r & 1) ? acc[3] : acc[2];
        float d  = (r & 2) ? s1 : s0;

        d += ip;
        // tanh(d) = 1 - 2/(exp(2d)+1)
        float e = __expf(2.0f * d);
        h = 1.0f - 2.0f / (e + 1.0f);

        // r<4 lanes write h_new[i_out] (swizzled word) to the other buffer
        if (r < 4)
            dst[i_out ^ (((i_out >> 5) & 7) << 2)] = h;

        ip = ip_next;
        __syncthreads();
    };

#pragma unroll 1
    for (int t = 0; t < SEQ; t += 2) {
        step(&hbuf[0][0], &hbuf[1][0], t + 1);
        step(&hbuf[1][0], &hbuf[0][0], t + 2);
    }

    if (r < 4) out[i_out] = h;
}

extern "C" void kernel_launch(void* const* d_in, const int* in_sizes, int n_in,
                              void* d_out, int out_size, void* d_ws, size_t ws_size,
                              hipStream_t stream)
{
    const int*   idx = (const int*)d_in[0];
    const float* emb = (const float*)d_in[1];
    const float* W   = (const float*)d_in[2];
    const float* b   = (const float*)d_in[3];
    float* out = (float*)d_out;
    float* inp = (float*)d_ws;  // SEQ*HID*4 = 512 KB scratch

    qrnn_phase1<<<SEQ, HID, 0, stream>>>(idx, emb, W, b, inp);
    qrnn_phase2<<<1, 512, 0, stream>>>(W, inp, out);
}